// Round 1
// baseline (196.425 us; speedup 1.0000x reference)
//
#include <hip/hip_runtime.h>
#include <hip/hip_bf16.h>

// Shapes: B=8, N=1024, D=768, H=12, HD=64, 3D=2304, tokens M=8192.
// Workspace layout (bytes), total 55,050,240 (~52.5 MiB):
//   xb   @ 0         : [8192][768]  bf16 (x * gate; reused as attn-out later)
//   wtq  @ 12582912  : [2304][768]  bf16 (W_qkv^T)
//   wtm  @ 16121856  : [768][768]   bf16 (W_msa^T)
//   qb   @ 17301504  : [B,H,N,64]   bf16 (q * SCALE * log2e)
//   kb   @ 29884416  : [B,H,N,64]   bf16 (k)
//   vt   @ 42467328  : [B,H,64,N]   bf16 (v, transposed)

typedef __attribute__((ext_vector_type(8))) short bf8;   // 8 x bf16 (4 VGPRs)
typedef __attribute__((ext_vector_type(4))) float f4;

#define QSCALE 0.1803368801111204f  // (1/8) * log2(e): exp2-domain logits
// No softmax max-shift needed: |logit| <= ~9 in exp2 domain -> exp2 <= ~500,
// row sums <= ~3e5 -- far from fp32/bf16 overflow; softmax is shift-invariant.

static __device__ __forceinline__ short bf16_of(float f) {
    union { float f; unsigned u; } a; a.f = f;
    unsigned r = a.u + 0x7FFFu + ((a.u >> 16) & 1u);  // RNE
    return (short)(r >> 16);
}

static __device__ __forceinline__ unsigned bfpk(float lo, float hi) {
    float2 t; t.x = lo; t.y = hi;
    __hip_bfloat162 b = __float22bfloat162_rn(t);
    union { __hip_bfloat162 b; unsigned u; } c; c.b = b;
    return c.u;
}

// async global->LDS, 16 bytes/lane. LDS dest must be wave-uniform base + lane*16.
static __device__ __forceinline__ void async16(const short* g, short* l) {
    __builtin_amdgcn_global_load_lds(
        (const __attribute__((address_space(1))) void*)g,
        (__attribute__((address_space(3))) void*)l, 16, 0, 0);
}

// ---- prep: fp32 -> bf16 bulk convert, gate folded in (8 elts/thread) ----
__global__ __launch_bounds__(256) void k_cvt(const float* __restrict__ src,
                                             const float* __restrict__ gate,
                                             short* __restrict__ dst, int n8) {
    int i = blockIdx.x * 256 + threadIdx.x;
    if (i >= n8) return;
    const float g = gate[i / 96];        // row = i*8/768
    const f4* sp = (const f4*)src;
    f4 a = sp[2 * i], b = sp[2 * i + 1];
    union { bf8 v; short h[8]; } o;
    o.h[0] = bf16_of(a[0] * g); o.h[1] = bf16_of(a[1] * g);
    o.h[2] = bf16_of(a[2] * g); o.h[3] = bf16_of(a[3] * g);
    o.h[4] = bf16_of(b[0] * g); o.h[5] = bf16_of(b[1] * g);
    o.h[6] = bf16_of(b[2] * g); o.h[7] = bf16_of(b[3] * g);
    ((bf8*)dst)[i] = o.v;
}

// ---- prep: W[K][E] fp32 -> Wt[E][K] bf16, LDS-tiled 64x64 ----
__global__ __launch_bounds__(256) void k_transpose(const float* __restrict__ w,
                                                   short* __restrict__ wt,
                                                   int K, int E) {
    __shared__ short t[64][65];
    const int k0 = blockIdx.y * 64, e0 = blockIdx.x * 64;
    const int tid = threadIdx.x;
#pragma unroll
    for (int p = 0; p < 16; ++p) {
        int idx = p * 256 + tid;
        int r = idx >> 6, c = idx & 63;
        t[r][c] = bf16_of(w[(k0 + r) * E + e0 + c]);
    }
    __syncthreads();
#pragma unroll
    for (int p = 0; p < 16; ++p) {
        int idx = p * 256 + tid;
        int r = idx >> 6, c = idx & 63;     // r = e offset, c = k offset
        wt[(e0 + r) * K + k0 + c] = t[c][r];
    }
}

// ---- 128x128 2-phase GEMM mainloop (kept for k_gemm_final: its 384 blocks
// are fully co-resident at 2 blocks/CU; 128^2+8phase is the unproven quadrant).
static __device__ __forceinline__ void gemm128(const short* __restrict__ gA,
                                               const short* __restrict__ gB,
                                               short* smem,
                                               f4 acc[4][4]) {
    const int tid = threadIdx.x, lane = tid & 63;
    const int l16 = lane & 15, quad = lane >> 4, rx = l16 & 7;
    const int wm = (tid >> 6) & 1, wn = tid >> 7;

    auto stage = [&](short* S, int k0) {
#pragma unroll
        for (int c = 0; c < 4; ++c) {
            int p = c * 256 + tid;
            int row = p >> 3, slot = p & 7;
            int gc = slot ^ (row & 7);
            async16(gA + row * 768 + k0 + gc * 8, S + p * 8);
            async16(gB + row * 768 + k0 + gc * 8, S + 8192 + p * 8);
        }
    };

    stage(smem, 0);
    for (int it = 0; it < 12; ++it) {
        __builtin_amdgcn_s_waitcnt(0);   // own DMA for tile[it] drained
        __syncthreads();                 // => tile[it] resident for all waves
        short* Sc = smem + (it & 1) * 16384;
        if (it + 1 < 12) stage(smem + ((it + 1) & 1) * 16384, (it + 1) * 64);
        const short* As = Sc;
        const short* Bs = Sc + 8192;
#pragma unroll
        for (int ks = 0; ks < 2; ++ks) {
            bf8 af[4], bfr[4];
#pragma unroll
            for (int mt = 0; mt < 4; ++mt)
                af[mt] = *(const bf8*)(As + (wm * 64 + mt * 16 + l16) * 64 +
                                       (((ks * 4 + quad) ^ rx) * 8));
#pragma unroll
            for (int nt = 0; nt < 4; ++nt)
                bfr[nt] = *(const bf8*)(Bs + (wn * 64 + nt * 16 + l16) * 64 +
                                        (((ks * 4 + quad) ^ rx) * 8));
#pragma unroll
            for (int mt = 0; mt < 4; ++mt)
#pragma unroll
                for (int nt = 0; nt < 4; ++nt)
                    acc[mt][nt] = __builtin_amdgcn_mfma_f32_16x16x32_bf16(
                        af[mt], bfr[nt], acc[mt][nt], 0, 0, 0);
        }
    }
    __syncthreads();   // callers may reuse smem right after return
}

// ---- QKV projection: [8192,768] @ [768,2304], 256x256 tile, BK=64,
//      8 waves (2Mx4N), 8-phase counted-vmcnt schedule (T2+T3+T4+T5):
// Per K-tile, 4 phases, quadrant order (m0n0)->(m0n1)->(m1n1)->(m1n0):
//   B-frags (32 VGPR) loaded ph1/ph2, held through ph4 => B LDS region of
//   tile t is dead after ph2's closing barrier. A-frags loaded per m-half
//   (ph1, ph3). Stage plan per tile t (1 half-tile per phase):
//     ph1: (t+1).A0 -> other buf   ph2: (t+1).A1 -> other buf
//     ph3: (t+2).B0 -> CURRENT buf (B dead since ph2)   ph4: (t+2).B1
//   vmcnt(4) once per K-tile at ph4 (leaves t+2's 2 B-halves in flight);
//   raw s_barrier only -- no vmcnt(0) drain in the main loop.
// LDS 128 KiB: buf b at b*32768 shorts = [A 256x64 | B 256x64], same
// slot^row XOR swizzle as gemm128 (pre-swizzled global src, linear LDS dest).
__global__ __launch_bounds__(512, 2) void k_gemm_qkv(
        const short* __restrict__ xb, const short* __restrict__ wtq,
        short* __restrict__ qb, short* __restrict__ kb, short* __restrict__ vt) {
    __shared__ short lds[65536];   // 128 KiB
    const int tid = threadIdx.x, lane = tid & 63;
    const int l16 = lane & 15, quad = lane >> 4, rx = l16 & 7;
    const int wv = tid >> 6, wm = wv >> 2, wn = wv & 3;   // 2M x 4N waves

    // XCD-aware bijective swizzle: 288 blocks = 8 XCDs x 36.
    // Each XCD gets 4 contiguous m-rows x 9 n-tiles: A-panels L2-local,
    // full B (3.5 MB) ~ one XCD L2.
    const int wg = blockIdx.x;
    const int swz = (wg & 7) * 36 + (wg >> 3);
    const int mI = swz / 9, nI = swz - mI * 9;
    const int m0 = mI * 256, n0 = nI * 256;

    const short* gA = xb + m0 * 768;
    const short* gB = wtq + n0 * 768;

    // stage one 128x64 half-tile: 512 thr x 2 x 16B; linear LDS dest,
    // inverse-swizzled global source (G21: both-sides-or-neither).
    auto stageHalf = [&](int buf, int isB, int half, const short* gsrc, int k0) {
        short* dst = lds + buf * 32768 + isB * 16384 + half * 8192;
        const short* src = gsrc + half * 98304 + k0;    // 128*768
#pragma unroll
        for (int j = 0; j < 2; ++j) {
            int p = j * 512 + tid;
            int row = p >> 3;
            int gc = (p & 7) ^ (row & 7);
            async16(src + row * 768 + gc * 8, dst + p * 8);
        }
    };

    f4 z = {0.f, 0.f, 0.f, 0.f};
    f4 acc[8][4];
#pragma unroll
    for (int mt = 0; mt < 8; ++mt)
#pragma unroll
        for (int nt = 0; nt < 4; ++nt) acc[mt][nt] = z;

    // prologue: t0 fully + t1.B0/B1 (6 halves = 12 loads); leave t1.B in flight
    stageHalf(0, 0, 0, gA, 0); stageHalf(0, 0, 1, gA, 0);
    stageHalf(0, 1, 0, gB, 0); stageHalf(0, 1, 1, gB, 0);
    stageHalf(1, 1, 0, gB, 64); stageHalf(1, 1, 1, gB, 64);
    asm volatile("s_waitcnt vmcnt(4)" ::: "memory");
    __builtin_amdgcn_s_barrier();

#pragma unroll 2
    for (int t = 0; t < 12; ++t) {
        const short* Ab = lds + (t & 1) * 32768;
        const short* Bb = Ab + 16384;
        bf8 af[4][2], bfr[4][2];

        auto rdA = [&](int mt, int ks) {
            return *(const bf8*)(Ab + (wm * 128 + mt * 16 + l16) * 64 +
                                 (((ks * 4 + quad) ^ rx) << 3));
        };
        auto rdB = [&](int nt, int ks) {
            return *(const bf8*)(Bb + (wn * 64 + nt * 16 + l16) * 64 +
                                 (((ks * 4 + quad) ^ rx) << 3));
        };

        // ---------- phase 1: quadrant (m-half 0, n-half 0) ----------
#pragma unroll
        for (int mt = 0; mt < 4; ++mt) { af[mt][0] = rdA(mt, 0); af[mt][1] = rdA(mt, 1); }
#pragma unroll
        for (int nt = 0; nt < 2; ++nt) { bfr[nt][0] = rdB(nt, 0); bfr[nt][1] = rdB(nt, 1); }
        if (t < 11) stageHalf((t + 1) & 1, 0, 0, gA, (t + 1) * 64);
        __builtin_amdgcn_s_barrier();
        __builtin_amdgcn_s_setprio(1);
#pragma unroll
        for (int mt = 0; mt < 4; ++mt)
#pragma unroll
            for (int nt = 0; nt < 2; ++nt) {
                acc[mt][nt] = __builtin_amdgcn_mfma_f32_16x16x32_bf16(
                    af[mt][0], bfr[nt][0], acc[mt][nt], 0, 0, 0);
                acc[mt][nt] = __builtin_amdgcn_mfma_f32_16x16x32_bf16(
                    af[mt][1], bfr[nt][1], acc[mt][nt], 0, 0, 0);
            }
        __builtin_amdgcn_s_setprio(0);
        __builtin_amdgcn_s_barrier();

        // ---------- phase 2: (m0, n1) ----------
#pragma unroll
        for (int nt = 2; nt < 4; ++nt) { bfr[nt][0] = rdB(nt, 0); bfr[nt][1] = rdB(nt, 1); }
        if (t < 11) stageHalf((t + 1) & 1, 0, 1, gA, (t + 1) * 64);
        __builtin_amdgcn_s_barrier();
        __builtin_amdgcn_s_setprio(1);
#pragma unroll
        for (int mt = 0; mt < 4; ++mt)
#pragma unroll
            for (int nt = 2; nt < 4; ++nt) {
                acc[mt][nt] = __builtin_amdgcn_mfma_f32_16x16x32_bf16(
                    af[mt][0], bfr[nt][0], acc[mt][nt], 0, 0, 0);
                acc[mt][nt] = __builtin_amdgcn_mfma_f32_16x16x32_bf16(
                    af[mt][1], bfr[nt][1], acc[mt][nt], 0, 0, 0);
            }
        __builtin_amdgcn_s_setprio(0);
        __builtin_amdgcn_s_barrier();

        // ---------- phase 3: (m1, n1); B reads of tile t done => can stage
        // (t+2).B0 into the CURRENT buffer ----------
#pragma unroll
        for (int mt = 0; mt < 4; ++mt) { af[mt][0] = rdA(mt + 4, 0); af[mt][1] = rdA(mt + 4, 1); }
        if (t < 10) stageHalf(t & 1, 1, 0, gB, (t + 2) * 64);
        __builtin_amdgcn_s_barrier();
        __builtin_amdgcn_s_setprio(1);
#pragma unroll
        for (int mt = 0; mt < 4; ++mt)
#pragma unroll
            for (int nt = 2; nt < 4; ++nt) {
                acc[mt + 4][nt] = __builtin_amdgcn_mfma_f32_16x16x32_bf16(
                    af[mt][0], bfr[nt][0], acc[mt + 4][nt], 0, 0, 0);
                acc[mt + 4][nt] = __builtin_amdgcn_mfma_f32_16x16x32_bf16(
                    af[mt][1], bfr[nt][1], acc[mt + 4][nt], 0, 0, 0);
            }
        __builtin_amdgcn_s_setprio(0);
        __builtin_amdgcn_s_barrier();

        // ---------- phase 4: (m1, n0); all frags in regs; counted vmcnt ----------
        if (t < 10) stageHalf(t & 1, 1, 1, gB, (t + 2) * 64);
        __builtin_amdgcn_s_barrier();
        __builtin_amdgcn_s_setprio(1);
#pragma unroll
        for (int mt = 0; mt < 4; ++mt)
#pragma unroll
            for (int nt = 0; nt < 2; ++nt) {
                acc[mt + 4][nt] = __builtin_amdgcn_mfma_f32_16x16x32_bf16(
                    af[mt][0], bfr[nt][0], acc[mt + 4][nt], 0, 0, 0);
                acc[mt + 4][nt] = __builtin_amdgcn_mfma_f32_16x16x32_bf16(
                    af[mt][1], bfr[nt][1], acc[mt + 4][nt], 0, 0, 0);
            }
        __builtin_amdgcn_s_setprio(0);
        // tile t+1 halves guaranteed resident; t+2's 2 B-halves stay in flight
        if (t < 10)       asm volatile("s_waitcnt vmcnt(4)" ::: "memory");
        else if (t == 10) asm volatile("s_waitcnt vmcnt(0)" ::: "memory");
        __builtin_amdgcn_s_barrier();
    }

    // ---------------- epilogue ----------------
    const int which = (n0 >= 1536) ? 2 : (n0 >= 768 ? 1 : 0);  // block-uniform
    if (which < 2) {
#pragma unroll
        for (int mt = 0; mt < 8; ++mt) {
#pragma unroll
            for (int r = 0; r < 4; ++r) {
                const int row = m0 + wm * 128 + mt * 16 + quad * 4 + r;  // token
                const int b = row >> 10, nn = row & 1023;
#pragma unroll
                for (int nt = 0; nt < 4; ++nt) {
                    const int ct = n0 + wn * 64 + nt * 16;   // col tile base
                    const int h = (ct - which * 768) >> 6;
                    const int hh = b * 12 + h;
                    const int hd = (ct & 63) + l16;
                    const float val = acc[mt][nt][r];
                    if (which == 0)
                        qb[(hh * 1024 + nn) * 64 + hd] = bf16_of(val * QSCALE);
                    else
                        kb[(hh * 1024 + nn) * 64 + hd] = bf16_of(val);
                }
            }
        }
    } else {
        // transpose 256x256 v-tile through LDS in two 128-dim passes
        const int b = m0 >> 10, nn0 = m0 & 1023;
        const int dg0 = n0 - 1536;
#pragma unroll
        for (int ch = 0; ch < 2; ++ch) {
            if ((wn >> 1) == ch) {
#pragma unroll
                for (int mt = 0; mt < 8; ++mt)
#pragma unroll
                    for (int nt = 0; nt < 4; ++nt)
#pragma unroll
                        for (int r = 0; r < 4; ++r) {
                            const int rl = wm * 128 + mt * 16 + quad * 4 + r;
                            const int cl = wn * 64 + nt * 16 + l16 - ch * 128;
                            lds[cl * 264 + rl] = bf16_of(acc[mt][nt][r]);
                        }
            }
            __syncthreads();
#pragma unroll
            for (int ph = 0; ph < 8; ++ph) {
                const int idx = ph * 512 + tid;
                const int cl = idx >> 5, ck = idx & 31;
                const int dg = dg0 + ch * 128 + cl;
                const int h = dg >> 6, hd = dg & 63;
                bf8 valv = *(const bf8*)(lds + cl * 264 + ck * 8);
                *(bf8*)(vt + ((b * 12 + h) * 64 + hd) * 1024 + nn0 + ck * 8) = valv;
            }
            __syncthreads();
        }
    }
}

// ---- final projection: [8192,768] @ [768,768] + bias -> fp32 out ----
__global__ __launch_bounds__(256) void k_gemm_final(
        const short* __restrict__ attn, const short* __restrict__ wtm,
        const float* __restrict__ bias, float* __restrict__ out) {
    __shared__ short smem[32768];
    const int lane = threadIdx.x & 63;
    const int l16 = lane & 15, quad = lane >> 4;
    const int wm = (threadIdx.x >> 6) & 1, wn = threadIdx.x >> 7;
    const int m0 = blockIdx.y * 128, n0 = blockIdx.x * 128;
    f4 z = {0.f, 0.f, 0.f, 0.f};
    f4 acc[4][4] = {{z,z,z,z},{z,z,z,z},{z,z,z,z},{z,z,z,z}};
    gemm128(attn + m0 * 768, wtm + n0 * 768, smem, acc);
#pragma unroll
    for (int mt = 0; mt < 4; ++mt) {
#pragma unroll
        for (int r = 0; r < 4; ++r) {
            const int row = m0 + wm * 64 + mt * 16 + quad * 4 + r;
#pragma unroll
            for (int nt = 0; nt < 4; ++nt) {
                const int e = n0 + wn * 64 + nt * 16 + l16;
                out[row * 768 + e] = acc[mt][nt][r] + bias[e];
            }
        }
    }
}

// ---- flash attention: 8 waves x 16 q-rows (512-thread block, more TLP),
//      double-buffered LDS K/V, no-shift softmax, MFMA rowsum,
//      sigma-permuted K rows => P lands in B-operand layout ----
// S-MFMA set A uses K rows sigma(p)=8*(p>>2)+(p&3), set B rows sigma(p)+4.
// Then lane(l16,quad) regs [A0..A3,B0..B3] = P[m=l16][j=quad*8+0..7]: the PV
// B-operand directly -- no cross-lane transform needed at all.
// LDS swizzle f(row)=4*((row>>3)&1)+(row&3) keeps sigma-reads at 2 lanes/bank.
// Dbuf handoff: explicit s_waitcnt(0) before the barrier (race-free protocol).
__global__ __launch_bounds__(512) void k_attn(const short* __restrict__ qb,
                                              const short* __restrict__ kb,
                                              const short* __restrict__ vt,
                                              short* __restrict__ attn) {
    __shared__ short Ks[2][4096];     // [64 keys][8 slots], f-swizzled
    __shared__ short Vs[2][4096];     // [64 dims][8 slots], f-swizzled
    const int tid = threadIdx.x, wave = tid >> 6, lane = tid & 63;
    const int l16 = lane & 15, quad = lane >> 4;
    const int bh = blockIdx.x;             // b*12 + h
    const int b = bh / 12, h = bh - b * 12;
    const int m_base = blockIdx.y * 128 + wave * 16;  // token in head
    const short* qh = qb + bh * 65536;
    const short* kh = kb + bh * 65536;
    const short* vh = vt + bh * 65536;     // [64][1024]

    // K-read offsets: set A row rA = sigma(l16), set B row rA+4 (f identical)
    const int rA = ((l16 >> 2) << 3) + (l16 & 3);
    const int fK = (((rA >> 3) & 1) << 2) + (rA & 3);
    const int sK = (quad ^ fK) * 8;              // slot*8 for d-chunk=quad
    const int oAlo = rA * 64 + sK;               // d 0..31
    const int oAhi = rA * 64 + (sK ^ 32);        // d 32..63 (slot^4)
    const int oBlo = oAlo + 256, oBhi = oAhi + 256;  // row+4
    // V-read offset: row = dt*16+l16, chunk = (jj>>3)+quad
    const int fV = (((l16 >> 3) & 1) << 2) + (l16 & 3);
    const int oV = l16 * 64 + ((quad ^ fV) * 8); // jj=32 -> ^32

    // Q^T b-frags (fixed for whole loop)
    const short* qp = qh + (m_base + l16) * 64 + quad * 8;
    bf8 qf0 = *(const bf8*)(qp);
    bf8 qf1 = *(const bf8*)(qp + 32);

    union { bf8 v; short h[8]; } onef;
#pragma unroll
    for (int i = 0; i < 8; ++i) onef.h[i] = (short)0x3F80;  // bf16 1.0

    f4 z = {0.f, 0.f, 0.f, 0.f};
    f4 acc[4] = {z, z, z, z};              // out^T: 4 d-tiles
    f4 accl = z;                           // P row-sums via ones-MFMA

    auto stage = [&](int buf, int j0) {
        // 512 threads, 512 chunks each for K and V (1 apiece)
        int idx = tid;
        int row = idx >> 3;
        int fr = (((row >> 3) & 1) << 2) + (row & 3);
        int gc = (idx & 7) ^ fr;            // slot idx&7 holds chunk gc
        async16(kh + (j0 + row) * 64 + gc * 8, Ks[buf] + idx * 8);
        async16(vh + row * 1024 + j0 + gc * 8, Vs[buf] + idx * 8);
    };

    stage(0, 0);
    int cur = 0;
    for (int it = 0; it < 16; ++it) {
        __builtin_amdgcn_s_waitcnt(0);         // own DMA for tile[cur] drained
        __syncthreads();                       // => tile[cur] resident for all
        if (it + 1 < 16) stage(cur ^ 1, (it + 1) * 64);  // overlaps compute
        const short* Kc = Ks[cur];
        const short* Vc = Vs[cur];

#pragma unroll
        for (int jj = 0; jj < 64; jj += 32) {
            const short* kjj = Kc + jj * 64;
            bf8 kAlo = *(const bf8*)(kjj + oAlo);
            bf8 kAhi = *(const bf8*)(kjj + oAhi);
            bf8 kBlo = *(const bf8*)(kjj + oBlo);
            bf8 kBhi = *(const bf8*)(kjj + oBhi);

            f4 sA = z, sB = z;
            sA = __builtin_amdgcn_mfma_f32_16x16x32_bf16(kAlo, qf0, sA, 0, 0, 0);
            sA = __builtin_amdgcn_mfma_f32_16x16x32_bf16(kAhi, qf1, sA, 0, 0, 0);
            sB = __builtin_amdgcn_mfma_f32_16x16x32_bf16(kBlo, qf0, sB, 0, 0, 0);
            sB = __builtin_amdgcn_mfma_f32_16x16x32_bf16(kBhi, qf1, sB, 0, 0, 0);
            // raw v_exp_f32; no shift (bounded logits, shift-invariant)
            float a0 = __builtin_amdgcn_exp2f(sA[0]);
            float a1 = __builtin_amdgcn_exp2f(sA[1]);
            float a2 = __builtin_amdgcn_exp2f(sA[2]);
            float a3 = __builtin_amdgcn_exp2f(sA[3]);
            float b0 = __builtin_amdgcn_exp2f(sB[0]);
            float b1 = __builtin_amdgcn_exp2f(sB[1]);
            float b2 = __builtin_amdgcn_exp2f(sB[2]);
            float b3 = __builtin_amdgcn_exp2f(sB[3]);
            union { bf8 v; unsigned u[4]; } p;
            p.u[0] = bfpk(a0, a1); p.u[1] = bfpk(a2, a3);
            p.u[2] = bfpk(b0, b1); p.u[3] = bfpk(b2, b3);
            accl = __builtin_amdgcn_mfma_f32_16x16x32_bf16(
                onef.v, p.v, accl, 0, 0, 0);

            // out^T += V^T @ P^T
#pragma unroll
            for (int dt = 0; dt < 4; ++dt) {
                bf8 vf = *(const bf8*)(Vc + dt * 1024 + (oV ^ (jj ? 32 : 0)));
                acc[dt] = __builtin_amdgcn_mfma_f32_16x16x32_bf16(
                    vf, p.v, acc[dt], 0, 0, 0);
            }
        }
        cur ^= 1;
    }

    const float inv = 1.f / accl[0];
    const int row = (b << 10) + m_base + l16;
    short* op = attn + row * 768 + h * 64 + quad * 4;
#pragma unroll
    for (int dt = 0; dt < 4; ++dt)
#pragma unroll
        for (int r = 0; r < 4; ++r)
            op[dt * 16 + r] = bf16_of(acc[dt][r] * inv);
}

extern "C" void kernel_launch(void* const* d_in, const int* in_sizes, int n_in,
                              void* d_out, int out_size, void* d_ws, size_t ws_size,
                              hipStream_t stream) {
    const float* x    = (const float*)d_in[0];   // [8,1024,768]
    const float* gate = (const float*)d_in[1];   // [8,1024]
    const float* Wqkv = (const float*)d_in[2];   // [768,2304]
    const float* Wmsa = (const float*)d_in[3];   // [768,768]
    const float* bmsa = (const float*)d_in[4];   // [768]
    float* out = (float*)d_out;

    char* ws = (char*)d_ws;
    short* xb  = (short*)(ws);
    short* wtq = (short*)(ws + 12582912);
    short* wtm = (short*)(ws + 16121856);
    short* qb  = (short*)(ws + 17301504);
    short* kb  = (short*)(ws + 29884416);
    short* vt  = (short*)(ws + 42467328);
    short* attn = xb;  // xb fully consumed by k_gemm_qkv before k_attn writes

    k_cvt<<<3072, 256, 0, stream>>>(x, gate, xb, 786432);           // 8192*768/8
    k_transpose<<<dim3(36, 12), 256, 0, stream>>>(Wqkv, wtq, 768, 2304);
    k_transpose<<<dim3(12, 12), 256, 0, stream>>>(Wmsa, wtm, 768, 768);
    k_gemm_qkv<<<288, 512, 0, stream>>>(xb, wtq, qb, kb, vt);
    k_attn<<<dim3(96, 8), 512, 0, stream>>>(qb, kb, vt, attn);
    k_gemm_final<<<dim3(6, 64), 256, 0, stream>>>(attn, wtm, bmsa, out);
}

// Round 2
// 186.066 us; speedup vs baseline: 1.0557x; 1.0557x over previous
//
#include <hip/hip_runtime.h>
#include <hip/hip_bf16.h>

// Shapes: B=8, N=1024, D=768, H=12, HD=64, 3D=2304, tokens M=8192.
// Workspace layout (bytes), total 55,050,240 (~52.5 MiB):
//   xb   @ 0         : [8192][768]  bf16 (x * gate; reused as attn-out later)
//   wtq  @ 12582912  : [2304][768]  bf16 (W_qkv^T)
//   wtm  @ 16121856  : [768][768]   bf16 (W_msa^T)
//   qb   @ 17301504  : [B,H,N,64]   bf16 (q * SCALE * log2e)
//   kb   @ 29884416  : [B,H,N,64]   bf16 (k)
//   vt   @ 42467328  : [B,H,64,N]   bf16 (v, transposed)

typedef __attribute__((ext_vector_type(8))) short bf8;   // 8 x bf16 (4 VGPRs)
typedef __attribute__((ext_vector_type(4))) float f4;

#define QSCALE 0.1803368801111204f  // (1/8) * log2(e): exp2-domain logits
// No softmax max-shift needed: |logit| <= ~9 in exp2 domain -> exp2 <= ~500,
// row sums <= ~3e5 -- far from fp32/bf16 overflow; softmax is shift-invariant.

static __device__ __forceinline__ short bf16_of(float f) {
    union { float f; unsigned u; } a; a.f = f;
    unsigned r = a.u + 0x7FFFu + ((a.u >> 16) & 1u);  // RNE
    return (short)(r >> 16);
}

static __device__ __forceinline__ unsigned bfpk(float lo, float hi) {
    float2 t; t.x = lo; t.y = hi;
    __hip_bfloat162 b = __float22bfloat162_rn(t);
    union { __hip_bfloat162 b; unsigned u; } c; c.b = b;
    return c.u;
}

// async global->LDS, 16 bytes/lane. LDS dest must be wave-uniform base + lane*16.
static __device__ __forceinline__ void async16(const short* g, short* l) {
    __builtin_amdgcn_global_load_lds(
        (const __attribute__((address_space(1))) void*)g,
        (__attribute__((address_space(3))) void*)l, 16, 0, 0);
}

// ---- prep: fp32 -> bf16 bulk convert, gate folded in (8 elts/thread) ----
__global__ __launch_bounds__(256) void k_cvt(const float* __restrict__ src,
                                             const float* __restrict__ gate,
                                             short* __restrict__ dst, int n8) {
    int i = blockIdx.x * 256 + threadIdx.x;
    if (i >= n8) return;
    const float g = gate[i / 96];        // row = i*8/768
    const f4* sp = (const f4*)src;
    f4 a = sp[2 * i], b = sp[2 * i + 1];
    union { bf8 v; short h[8]; } o;
    o.h[0] = bf16_of(a[0] * g); o.h[1] = bf16_of(a[1] * g);
    o.h[2] = bf16_of(a[2] * g); o.h[3] = bf16_of(a[3] * g);
    o.h[4] = bf16_of(b[0] * g); o.h[5] = bf16_of(b[1] * g);
    o.h[6] = bf16_of(b[2] * g); o.h[7] = bf16_of(b[3] * g);
    ((bf8*)dst)[i] = o.v;
}

// ---- prep: W[K][E] fp32 -> Wt[E][K] bf16, LDS-tiled 64x64 ----
__global__ __launch_bounds__(256) void k_transpose(const float* __restrict__ w,
                                                   short* __restrict__ wt,
                                                   int K, int E) {
    __shared__ short t[64][65];
    const int k0 = blockIdx.y * 64, e0 = blockIdx.x * 64;
    const int tid = threadIdx.x;
#pragma unroll
    for (int p = 0; p < 16; ++p) {
        int idx = p * 256 + tid;
        int r = idx >> 6, c = idx & 63;
        t[r][c] = bf16_of(w[(k0 + r) * E + e0 + c]);
    }
    __syncthreads();
#pragma unroll
    for (int p = 0; p < 16; ++p) {
        int idx = p * 256 + tid;
        int r = idx >> 6, c = idx & 63;     // r = e offset, c = k offset
        wt[(e0 + r) * K + k0 + c] = t[c][r];
    }
}

// ---- 128x128 2-phase GEMM mainloop (kept for k_gemm_final: its 384 blocks
// are fully co-resident at 2 blocks/CU).
static __device__ __forceinline__ void gemm128(const short* __restrict__ gA,
                                               const short* __restrict__ gB,
                                               short* smem,
                                               f4 acc[4][4]) {
    const int tid = threadIdx.x, lane = tid & 63;
    const int l16 = lane & 15, quad = lane >> 4, rx = l16 & 7;
    const int wm = (tid >> 6) & 1, wn = tid >> 7;

    auto stage = [&](short* S, int k0) {
#pragma unroll
        for (int c = 0; c < 4; ++c) {
            int p = c * 256 + tid;
            int row = p >> 3, slot = p & 7;
            int gc = slot ^ (row & 7);
            async16(gA + row * 768 + k0 + gc * 8, S + p * 8);
            async16(gB + row * 768 + k0 + gc * 8, S + 8192 + p * 8);
        }
    };

    stage(smem, 0);
    for (int it = 0; it < 12; ++it) {
        __builtin_amdgcn_s_waitcnt(0);   // own DMA for tile[it] drained
        __syncthreads();                 // => tile[it] resident for all waves
        short* Sc = smem + (it & 1) * 16384;
        if (it + 1 < 12) stage(smem + ((it + 1) & 1) * 16384, (it + 1) * 64);
        const short* As = Sc;
        const short* Bs = Sc + 8192;
#pragma unroll
        for (int ks = 0; ks < 2; ++ks) {
            bf8 af[4], bfr[4];
#pragma unroll
            for (int mt = 0; mt < 4; ++mt)
                af[mt] = *(const bf8*)(As + (wm * 64 + mt * 16 + l16) * 64 +
                                       (((ks * 4 + quad) ^ rx) * 8));
#pragma unroll
            for (int nt = 0; nt < 4; ++nt)
                bfr[nt] = *(const bf8*)(Bs + (wn * 64 + nt * 16 + l16) * 64 +
                                        (((ks * 4 + quad) ^ rx) * 8));
#pragma unroll
            for (int mt = 0; mt < 4; ++mt)
#pragma unroll
                for (int nt = 0; nt < 4; ++nt)
                    acc[mt][nt] = __builtin_amdgcn_mfma_f32_16x16x32_bf16(
                        af[mt], bfr[nt], acc[mt][nt], 0, 0, 0);
        }
    }
    __syncthreads();   // callers may reuse smem right after return
}

// ---- QKV projection: [8192,768] @ [768,2304], tile 256x288, BK=64,
//      grid EXACTLY 256 blocks (32 m x 8 n) -> no dispatch tail (round-1
//      counters: 288 blocks @ 1/CU spent ~60% of time in a 32-block round).
// 8 waves as 4M x 2N; per-wave 64x144 output = acc[4][9] (144 acc regs;
// peak live ~236 <= 256 -> still 2 waves/SIMD).
// Phases per K-tile: (m0,n0-4)(m1,n0-4)(m0,n5-8)(m1,n5-8); 20/20/16/16 MFMA.
//   reads: ph1 af[0..1]+bfr[0..4] (14), ph2 af[2..3] (4), ph3 bfr[5..8] (8).
//   stage slots: ph1 (t+1).B1  ph2 (t+1).A0  ph3 (t+1).A1  ph4 (t+2).B0.
//   Safety: B-half rows of tile t are consumed by the phase BEFORE the slot
//   that overwrites/stages them (bfr[5..8] consumed in ph3 => ph4 B0-stage ok).
// B staging: half = 144x64 = 1152 chunks; waves 0-1 do 3 calls, 2-7 do 2 ->
//   per-wave counted vmcnt(3)/vmcnt(2) at end of tile (never 0 until t==10).
// LDS 136 KiB: buf b at b*34816 shorts = [A 256x64 | B 288x64], slot^row XOR
// swizzle (pre-swizzled global src, linear LDS dest).
__global__ __launch_bounds__(512, 2) void k_gemm_qkv(
        const short* __restrict__ xb, const short* __restrict__ wtq,
        short* __restrict__ qb, short* __restrict__ kb, short* __restrict__ vt) {
    __shared__ short lds[69632];   // 136 KiB
    const int tid = threadIdx.x, lane = tid & 63;
    const int l16 = lane & 15, quad = lane >> 4, rx = l16 & 7;
    const int wv = tid >> 6, wm = wv >> 1, wn = wv & 1;   // 4M x 2N waves

    // XCD-aware bijective swizzle: 256 blocks = 8 XCDs x 32.
    // Each XCD: 4 contiguous m-panels x all 8 n-panels (B = 3.4 MB ~ one L2).
    const int wg = blockIdx.x;
    const int swz = (wg & 7) * 32 + (wg >> 3);
    const int mI = swz >> 3, nI = swz & 7;
    const int m0 = mI * 256, n0 = nI * 288;

    const short* gA = xb + m0 * 768;
    const short* gB = wtq + n0 * 768;

    // stage one 128x64 A half-tile: 1024 chunks, 2/thread.
    auto stageA = [&](int buf, int half, int k0) {
        short* dst = lds + buf * 34816 + half * 8192;
        const short* src = gA + half * 98304 + k0;
#pragma unroll
        for (int j = 0; j < 2; ++j) {
            int p = j * 512 + tid;
            int row = p >> 3;
            int gc = (p & 7) ^ (row & 7);
            async16(src + row * 768 + gc * 8, dst + p * 8);
        }
    };
    // stage one 144x64 B half-tile: 1152 chunks; waves 0-1 take the extra 128.
    auto stageB = [&](int buf, int half, int k0) {
        short* dst = lds + buf * 34816 + 16384 + half * 9216;
        const short* src = gB + half * 110592 + k0;
#pragma unroll
        for (int j = 0; j < 2; ++j) {
            int p = j * 512 + tid;
            int row = p >> 3;
            int gc = (p & 7) ^ (row & 7);
            async16(src + row * 768 + gc * 8, dst + p * 8);
        }
        if (tid < 128) {              // waves 0,1: wave-uniform, lane-contig
            int p = 1024 + tid;
            int row = p >> 3;
            int gc = (p & 7) ^ (row & 7);
            async16(src + row * 768 + gc * 8, dst + p * 8);
        }
    };

    f4 z = {0.f, 0.f, 0.f, 0.f};
    f4 acc[4][9];
#pragma unroll
    for (int mf = 0; mf < 4; ++mf)
#pragma unroll
        for (int nf = 0; nf < 9; ++nf) acc[mf][nf] = z;

    // prologue: t0 fully + t1.B0; leave t1.B0 in flight
    stageA(0, 0, 0); stageA(0, 1, 0);
    stageB(0, 0, 0); stageB(0, 1, 0);
    stageB(1, 0, 64);
    if (wv < 2) asm volatile("s_waitcnt vmcnt(3)" ::: "memory");
    else        asm volatile("s_waitcnt vmcnt(2)" ::: "memory");
    __builtin_amdgcn_s_barrier();

#pragma unroll 2
    for (int t = 0; t < 12; ++t) {
        const short* Ab = lds + (t & 1) * 34816;
        const short* Bb = Ab + 16384;
        auto rdA = [&](int mf, int ks) {
            return *(const bf8*)(Ab + (wm * 64 + mf * 16 + l16) * 64 +
                                 (((ks * 4 + quad) ^ rx) << 3));
        };
        auto rdB = [&](int nf, int ks) {
            return *(const bf8*)(Bb + (wn * 144 + nf * 16 + l16) * 64 +
                                 (((ks * 4 + quad) ^ rx) << 3));
        };
        bf8 af[4][2], bfr[9][2];

        // ---------- phase 1: (mf 0-1) x (nf 0-4) ----------
#pragma unroll
        for (int mf = 0; mf < 2; ++mf) { af[mf][0] = rdA(mf, 0); af[mf][1] = rdA(mf, 1); }
#pragma unroll
        for (int nf = 0; nf < 5; ++nf) { bfr[nf][0] = rdB(nf, 0); bfr[nf][1] = rdB(nf, 1); }
        if (t < 11) stageB((t + 1) & 1, 1, (t + 1) * 64);
        __builtin_amdgcn_s_barrier();
        __builtin_amdgcn_s_setprio(1);
#pragma unroll
        for (int mf = 0; mf < 2; ++mf)
#pragma unroll
            for (int nf = 0; nf < 5; ++nf) {
                acc[mf][nf] = __builtin_amdgcn_mfma_f32_16x16x32_bf16(
                    af[mf][0], bfr[nf][0], acc[mf][nf], 0, 0, 0);
                acc[mf][nf] = __builtin_amdgcn_mfma_f32_16x16x32_bf16(
                    af[mf][1], bfr[nf][1], acc[mf][nf], 0, 0, 0);
            }
        __builtin_amdgcn_s_setprio(0);
        __builtin_amdgcn_s_barrier();

        // ---------- phase 2: (mf 2-3) x (nf 0-4) ----------
#pragma unroll
        for (int mf = 2; mf < 4; ++mf) { af[mf][0] = rdA(mf, 0); af[mf][1] = rdA(mf, 1); }
        if (t < 11) stageA((t + 1) & 1, 0, (t + 1) * 64);
        __builtin_amdgcn_s_barrier();
        __builtin_amdgcn_s_setprio(1);
#pragma unroll
        for (int mf = 2; mf < 4; ++mf)
#pragma unroll
            for (int nf = 0; nf < 5; ++nf) {
                acc[mf][nf] = __builtin_amdgcn_mfma_f32_16x16x32_bf16(
                    af[mf][0], bfr[nf][0], acc[mf][nf], 0, 0, 0);
                acc[mf][nf] = __builtin_amdgcn_mfma_f32_16x16x32_bf16(
                    af[mf][1], bfr[nf][1], acc[mf][nf], 0, 0, 0);
            }
        __builtin_amdgcn_s_setprio(0);
        __builtin_amdgcn_s_barrier();

        // ---------- phase 3: (mf 0-1) x (nf 5-8) ----------
#pragma unroll
        for (int nf = 5; nf < 9; ++nf) { bfr[nf][0] = rdB(nf, 0); bfr[nf][1] = rdB(nf, 1); }
        if (t < 11) stageA((t + 1) & 1, 1, (t + 1) * 64);
        __builtin_amdgcn_s_barrier();
        __builtin_amdgcn_s_setprio(1);
#pragma unroll
        for (int mf = 0; mf < 2; ++mf)
#pragma unroll
            for (int nf = 5; nf < 9; ++nf) {
                acc[mf][nf] = __builtin_amdgcn_mfma_f32_16x16x32_bf16(
                    af[mf][0], bfr[nf][0], acc[mf][nf], 0, 0, 0);
                acc[mf][nf] = __builtin_amdgcn_mfma_f32_16x16x32_bf16(
                    af[mf][1], bfr[nf][1], acc[mf][nf], 0, 0, 0);
            }
        __builtin_amdgcn_s_setprio(0);
        __builtin_amdgcn_s_barrier();

        // ---------- phase 4: (mf 2-3) x (nf 5-8); counted vmcnt ----------
        if (t < 10) stageB(t & 1, 0, (t + 2) * 64);
        __builtin_amdgcn_s_barrier();
        __builtin_amdgcn_s_setprio(1);
#pragma unroll
        for (int mf = 2; mf < 4; ++mf)
#pragma unroll
            for (int nf = 5; nf < 9; ++nf) {
                acc[mf][nf] = __builtin_amdgcn_mfma_f32_16x16x32_bf16(
                    af[mf][0], bfr[nf][0], acc[mf][nf], 0, 0, 0);
                acc[mf][nf] = __builtin_amdgcn_mfma_f32_16x16x32_bf16(
                    af[mf][1], bfr[nf][1], acc[mf][nf], 0, 0, 0);
            }
        __builtin_amdgcn_s_setprio(0);
        // retire everything except ph4's (t+2).B0 -> tile t+1 fully resident
        if (t < 10) {
            if (wv < 2) asm volatile("s_waitcnt vmcnt(3)" ::: "memory");
            else        asm volatile("s_waitcnt vmcnt(2)" ::: "memory");
        } else if (t == 10) {
            asm volatile("s_waitcnt vmcnt(0)" ::: "memory");
        }
        __builtin_amdgcn_s_barrier();
    }

    // ---------------- epilogue ----------------
    const int bI = m0 >> 10, nn0 = m0 & 1023;
    // q/k frags (per-frag type; 768 % 16 == 0 so frags never straddle)
#pragma unroll
    for (int nf = 0; nf < 9; ++nf) {
        const int ct = n0 + wn * 144 + nf * 16;
        if (ct < 1536) {
            const int which = (ct >= 768) ? 1 : 0;
            const int h = (ct - which * 768) >> 6;
            const int hd = (ct & 63) + l16;
            short* dst = (which ? kb : qb) + ((bI * 12 + h) * 1024) * 64 + hd;
#pragma unroll
            for (int mf = 0; mf < 4; ++mf)
#pragma unroll
                for (int r = 0; r < 4; ++r) {
                    const int nn = nn0 + wm * 64 + mf * 16 + quad * 4 + r;
                    const float val = acc[mf][nf][r];
                    dst[nn * 64] = bf16_of(which ? val : val * QSCALE);
                }
        }
    }
    // v frags: transpose through LDS in 96-col passes (96x264 shorts = 50 KB)
    const int vstart = (n0 >= 1536) ? n0 : 1536;
    const int npass = (n0 + 288 > vstart) ? (n0 + 288 - vstart) / 96 : 0;
    for (int p = 0; p < npass; ++p) {
        __syncthreads();
        const int c0 = vstart + p * 96;
#pragma unroll
        for (int nf = 0; nf < 9; ++nf) {
            const int ct = n0 + wn * 144 + nf * 16;
            if (ct >= c0 && ct < c0 + 96) {
                const int lc = ct - c0 + l16;
#pragma unroll
                for (int mf = 0; mf < 4; ++mf)
#pragma unroll
                    for (int r = 0; r < 4; ++r) {
                        const int rl = wm * 64 + mf * 16 + quad * 4 + r;
                        lds[lc * 264 + rl] = bf16_of(acc[mf][nf][r]);
                    }
            }
        }
        __syncthreads();
        const int vg0 = c0 - 1536;
#pragma unroll
        for (int u = 0; u < 6; ++u) {
            const int idx = u * 512 + tid;       // 96 cols x 32 chunks
            const int lc = idx >> 5, ck = idx & 31;
            const int vg = vg0 + lc;
            const int h = vg >> 6, hd = vg & 63;
            bf8 vv = *(const bf8*)(lds + lc * 264 + ck * 8);
            *(bf8*)(vt + ((bI * 12 + h) * 64 + hd) * 1024 + nn0 + ck * 8) = vv;
        }
    }
}

// ---- final projection: [8192,768] @ [768,768] + bias -> fp32 out ----
__global__ __launch_bounds__(256) void k_gemm_final(
        const short* __restrict__ attn, const short* __restrict__ wtm,
        const float* __restrict__ bias, float* __restrict__ out) {
    __shared__ short smem[32768];
    const int lane = threadIdx.x & 63;
    const int l16 = lane & 15, quad = lane >> 4;
    const int wm = (threadIdx.x >> 6) & 1, wn = threadIdx.x >> 7;
    const int m0 = blockIdx.y * 128, n0 = blockIdx.x * 128;
    f4 z = {0.f, 0.f, 0.f, 0.f};
    f4 acc[4][4] = {{z,z,z,z},{z,z,z,z},{z,z,z,z},{z,z,z,z}};
    gemm128(attn + m0 * 768, wtm + n0 * 768, smem, acc);
#pragma unroll
    for (int mt = 0; mt < 4; ++mt) {
#pragma unroll
        for (int r = 0; r < 4; ++r) {
            const int row = m0 + wm * 64 + mt * 16 + quad * 4 + r;
#pragma unroll
            for (int nt = 0; nt < 4; ++nt) {
                const int e = n0 + wn * 64 + nt * 16 + l16;
                out[row * 768 + e] = acc[mt][nt][r] + bias[e];
            }
        }
    }
}

// ---- flash attention: 8 waves x 16 q-rows (512-thread block, more TLP),
//      double-buffered LDS K/V, no-shift softmax, MFMA rowsum,
//      sigma-permuted K rows => P lands in B-operand layout ----
// S-MFMA set A uses K rows sigma(p)=8*(p>>2)+(p&3), set B rows sigma(p)+4.
// Then lane(l16,quad) regs [A0..A3,B0..B3] = P[m=l16][j=quad*8+0..7]: the PV
// B-operand directly -- no cross-lane transform needed at all.
// LDS swizzle f(row)=4*((row>>3)&1)+(row&3) keeps sigma-reads at 2 lanes/bank.
// Dbuf handoff: explicit s_waitcnt(0) before the barrier (race-free protocol).
__global__ __launch_bounds__(512) void k_attn(const short* __restrict__ qb,
                                              const short* __restrict__ kb,
                                              const short* __restrict__ vt,
                                              short* __restrict__ attn) {
    __shared__ short Ks[2][4096];     // [64 keys][8 slots], f-swizzled
    __shared__ short Vs[2][4096];     // [64 dims][8 slots], f-swizzled
    const int tid = threadIdx.x, wave = tid >> 6, lane = tid & 63;
    const int l16 = lane & 15, quad = lane >> 4;
    const int bh = blockIdx.x;             // b*12 + h
    const int b = bh / 12, h = bh - b * 12;
    const int m_base = blockIdx.y * 128 + wave * 16;  // token in head
    const short* qh = qb + bh * 65536;
    const short* kh = kb + bh * 65536;
    const short* vh = vt + bh * 65536;     // [64][1024]

    // K-read offsets: set A row rA = sigma(l16), set B row rA+4 (f identical)
    const int rA = ((l16 >> 2) << 3) + (l16 & 3);
    const int fK = (((rA >> 3) & 1) << 2) + (rA & 3);
    const int sK = (quad ^ fK) * 8;              // slot*8 for d-chunk=quad
    const int oAlo = rA * 64 + sK;               // d 0..31
    const int oAhi = rA * 64 + (sK ^ 32);        // d 32..63 (slot^4)
    const int oBlo = oAlo + 256, oBhi = oAhi + 256;  // row+4
    // V-read offset: row = dt*16+l16, chunk = (jj>>3)+quad
    const int fV = (((l16 >> 3) & 1) << 2) + (l16 & 3);
    const int oV = l16 * 64 + ((quad ^ fV) * 8); // jj=32 -> ^32

    // Q^T b-frags (fixed for whole loop)
    const short* qp = qh + (m_base + l16) * 64 + quad * 8;
    bf8 qf0 = *(const bf8*)(qp);
    bf8 qf1 = *(const bf8*)(qp + 32);

    union { bf8 v; short h[8]; } onef;
#pragma unroll
    for (int i = 0; i < 8; ++i) onef.h[i] = (short)0x3F80;  // bf16 1.0

    f4 z = {0.f, 0.f, 0.f, 0.f};
    f4 acc[4] = {z, z, z, z};              // out^T: 4 d-tiles
    f4 accl = z;                           // P row-sums via ones-MFMA

    auto stage = [&](int buf, int j0) {
        // 512 threads, 512 chunks each for K and V (1 apiece)
        int idx = tid;
        int row = idx >> 3;
        int fr = (((row >> 3) & 1) << 2) + (row & 3);
        int gc = (idx & 7) ^ fr;            // slot idx&7 holds chunk gc
        async16(kh + (j0 + row) * 64 + gc * 8, Ks[buf] + idx * 8);
        async16(vh + row * 1024 + j0 + gc * 8, Vs[buf] + idx * 8);
    };

    stage(0, 0);
    int cur = 0;
    for (int it = 0; it < 16; ++it) {
        __builtin_amdgcn_s_waitcnt(0);         // own DMA for tile[cur] drained
        __syncthreads();                       // => tile[cur] resident for all
        if (it + 1 < 16) stage(cur ^ 1, (it + 1) * 64);  // overlaps compute
        const short* Kc = Ks[cur];
        const short* Vc = Vs[cur];

#pragma unroll
        for (int jj = 0; jj < 64; jj += 32) {
            const short* kjj = Kc + jj * 64;
            bf8 kAlo = *(const bf8*)(kjj + oAlo);
            bf8 kAhi = *(const bf8*)(kjj + oAhi);
            bf8 kBlo = *(const bf8*)(kjj + oBlo);
            bf8 kBhi = *(const bf8*)(kjj + oBhi);

            f4 sA = z, sB = z;
            sA = __builtin_amdgcn_mfma_f32_16x16x32_bf16(kAlo, qf0, sA, 0, 0, 0);
            sA = __builtin_amdgcn_mfma_f32_16x16x32_bf16(kAhi, qf1, sA, 0, 0, 0);
            sB = __builtin_amdgcn_mfma_f32_16x16x32_bf16(kBlo, qf0, sB, 0, 0, 0);
            sB = __builtin_amdgcn_mfma_f32_16x16x32_bf16(kBhi, qf1, sB, 0, 0, 0);
            // raw v_exp_f32; no shift (bounded logits, shift-invariant)
            float a0 = __builtin_amdgcn_exp2f(sA[0]);
            float a1 = __builtin_amdgcn_exp2f(sA[1]);
            float a2 = __builtin_amdgcn_exp2f(sA[2]);
            float a3 = __builtin_amdgcn_exp2f(sA[3]);
            float b0 = __builtin_amdgcn_exp2f(sB[0]);
            float b1 = __builtin_amdgcn_exp2f(sB[1]);
            float b2 = __builtin_amdgcn_exp2f(sB[2]);
            float b3 = __builtin_amdgcn_exp2f(sB[3]);
            union { bf8 v; unsigned u[4]; } p;
            p.u[0] = bfpk(a0, a1); p.u[1] = bfpk(a2, a3);
            p.u[2] = bfpk(b0, b1); p.u[3] = bfpk(b2, b3);
            accl = __builtin_amdgcn_mfma_f32_16x16x32_bf16(
                onef.v, p.v, accl, 0, 0, 0);

            // out^T += V^T @ P^T
#pragma unroll
            for (int dt = 0; dt < 4; ++dt) {
                bf8 vf = *(const bf8*)(Vc + dt * 1024 + (oV ^ (jj ? 32 : 0)));
                acc[dt] = __builtin_amdgcn_mfma_f32_16x16x32_bf16(
                    vf, p.v, acc[dt], 0, 0, 0);
            }
        }
        cur ^= 1;
    }

    const float inv = 1.f / accl[0];
    const int row = (b << 10) + m_base + l16;
    short* op = attn + row * 768 + h * 64 + quad * 4;
#pragma unroll
    for (int dt = 0; dt < 4; ++dt)
#pragma unroll
        for (int r = 0; r < 4; ++r)
            op[dt * 16 + r] = bf16_of(acc[dt][r] * inv);
}

extern "C" void kernel_launch(void* const* d_in, const int* in_sizes, int n_in,
                              void* d_out, int out_size, void* d_ws, size_t ws_size,
                              hipStream_t stream) {
    const float* x    = (const float*)d_in[0];   // [8,1024,768]
    const float* gate = (const float*)d_in[1];   // [8,1024]
    const float* Wqkv = (const float*)d_in[2];   // [768,2304]
    const float* Wmsa = (const float*)d_in[3];   // [768,768]
    const float* bmsa = (const float*)d_in[4];   // [768]
    float* out = (float*)d_out;

    char* ws = (char*)d_ws;
    short* xb  = (short*)(ws);
    short* wtq = (short*)(ws + 12582912);
    short* wtm = (short*)(ws + 16121856);
    short* qb  = (short*)(ws + 17301504);
    short* kb  = (short*)(ws + 29884416);
    short* vt  = (short*)(ws + 42467328);
    short* attn = xb;  // xb fully consumed by k_gemm_qkv before k_attn writes

    k_cvt<<<3072, 256, 0, stream>>>(x, gate, xb, 786432);           // 8192*768/8
    k_transpose<<<dim3(36, 12), 256, 0, stream>>>(Wqkv, wtq, 768, 2304);
    k_transpose<<<dim3(12, 12), 256, 0, stream>>>(Wmsa, wtm, 768, 768);
    k_gemm_qkv<<<256, 512, 0, stream>>>(xb, wtq, qb, kb, vt);
    k_attn<<<dim3(96, 8), 512, 0, stream>>>(qb, kb, vt, attn);
    k_gemm_final<<<dim3(6, 64), 256, 0, stream>>>(attn, wtm, bmsa, out);
}

// Round 3
// 175.662 us; speedup vs baseline: 1.1182x; 1.0592x over previous
//
#include <hip/hip_runtime.h>
#include <hip/hip_bf16.h>

// Shapes: B=8, N=1024, D=768, H=12, HD=64, 3D=2304, tokens M=8192.
// Workspace layout (bytes), total 55,050,240 (~52.5 MiB):
//   xb   @ 0         : [8192][768]  bf16 (x * gate; reused as attn-out later)
//   wtq  @ 12582912  : [2304][768]  bf16 (W_qkv^T)
//   wtm  @ 16121856  : [768][768]   bf16 (W_msa^T)
//   qb   @ 17301504  : [B,H,N,64]   bf16 (q * SCALE * log2e)
//   kb   @ 29884416  : [B,H,N,64]   bf16 (k)
//   vt   @ 42467328  : [B,H,64,N]   bf16 (v, transposed)

typedef __attribute__((ext_vector_type(8))) short bf8;   // 8 x bf16 (4 VGPRs)
typedef __attribute__((ext_vector_type(4))) float f4;

#define QSCALE 0.1803368801111204f  // (1/8) * log2(e): exp2-domain logits
// No softmax max-shift needed: |logit| <= ~9 in exp2 domain -> exp2 <= ~500,
// row sums <= ~3e5 -- far from fp32/bf16 overflow; softmax is shift-invariant.

static __device__ __forceinline__ short bf16_of(float f) {
    union { float f; unsigned u; } a; a.f = f;
    unsigned r = a.u + 0x7FFFu + ((a.u >> 16) & 1u);  // RNE
    return (short)(r >> 16);
}

static __device__ __forceinline__ unsigned bfpk(float lo, float hi) {
    float2 t; t.x = lo; t.y = hi;
    __hip_bfloat162 b = __float22bfloat162_rn(t);
    union { __hip_bfloat162 b; unsigned u; } c; c.b = b;
    return c.u;
}

// async global->LDS, 16 bytes/lane. LDS dest must be wave-uniform base + lane*16.
static __device__ __forceinline__ void async16(const short* g, short* l) {
    __builtin_amdgcn_global_load_lds(
        (const __attribute__((address_space(1))) void*)g,
        (__attribute__((address_space(3))) void*)l, 16, 0, 0);
}

// ---- merged prep kernel: cvt (blocks 0..3071) + Wqkv transpose (3072..3503)
//      + Wmsa transpose (3504..3647). Independent work; saves 2 launch gaps.
static __device__ __forceinline__ void transpose64(
        const float* __restrict__ w, short* __restrict__ wt,
        int K, int E, int k0, int e0, int tid, short (*t)[65]) {
#pragma unroll
    for (int p = 0; p < 16; ++p) {
        int idx = p * 256 + tid;
        int r = idx >> 6, c = idx & 63;
        t[r][c] = bf16_of(w[(k0 + r) * E + e0 + c]);
    }
    __syncthreads();
#pragma unroll
    for (int p = 0; p < 16; ++p) {
        int idx = p * 256 + tid;
        int r = idx >> 6, c = idx & 63;     // r = e offset, c = k offset
        wt[(e0 + r) * K + k0 + c] = t[c][r];
    }
}

__global__ __launch_bounds__(256) void k_prep(
        const float* __restrict__ x, const float* __restrict__ gate,
        short* __restrict__ xb,
        const float* __restrict__ Wqkv, short* __restrict__ wtq,
        const float* __restrict__ Wmsa, short* __restrict__ wtm) {
    __shared__ short t[64][65];
    const int bid = blockIdx.x, tid = threadIdx.x;
    if (bid < 3072) {
        int i = bid * 256 + tid;              // 786432 = 8192*768/8 exactly
        const float g = gate[i / 96];         // row = i*8/768
        const f4* sp = (const f4*)x;
        f4 a = sp[2 * i], b = sp[2 * i + 1];
        union { bf8 v; short h[8]; } o;
        o.h[0] = bf16_of(a[0] * g); o.h[1] = bf16_of(a[1] * g);
        o.h[2] = bf16_of(a[2] * g); o.h[3] = bf16_of(a[3] * g);
        o.h[4] = bf16_of(b[0] * g); o.h[5] = bf16_of(b[1] * g);
        o.h[6] = bf16_of(b[2] * g); o.h[7] = bf16_of(b[3] * g);
        ((bf8*)xb)[i] = o.v;
    } else if (bid < 3504) {
        int tt = bid - 3072;                  // 432 = 36 x 12
        transpose64(Wqkv, wtq, 768, 2304, (tt / 36) * 64, (tt % 36) * 64, tid, t);
    } else {
        int tt = bid - 3504;                  // 144 = 12 x 12
        transpose64(Wmsa, wtm, 768, 768, (tt / 12) * 64, (tt % 12) * 64, tid, t);
    }
}

// ---- 128x128 2-phase GEMM mainloop (kept for k_gemm_final: its 384 blocks
// are fully co-resident at 2 blocks/CU).
static __device__ __forceinline__ void gemm128(const short* __restrict__ gA,
                                               const short* __restrict__ gB,
                                               short* smem,
                                               f4 acc[4][4]) {
    const int tid = threadIdx.x, lane = tid & 63;
    const int l16 = lane & 15, quad = lane >> 4, rx = l16 & 7;
    const int wm = (tid >> 6) & 1, wn = tid >> 7;

    auto stage = [&](short* S, int k0) {
#pragma unroll
        for (int c = 0; c < 4; ++c) {
            int p = c * 256 + tid;
            int row = p >> 3, slot = p & 7;
            int gc = slot ^ (row & 7);
            async16(gA + row * 768 + k0 + gc * 8, S + p * 8);
            async16(gB + row * 768 + k0 + gc * 8, S + 8192 + p * 8);
        }
    };

    stage(smem, 0);
    for (int it = 0; it < 12; ++it) {
        __builtin_amdgcn_s_waitcnt(0);   // own DMA for tile[it] drained
        __syncthreads();                 // => tile[it] resident for all waves
        short* Sc = smem + (it & 1) * 16384;
        if (it + 1 < 12) stage(smem + ((it + 1) & 1) * 16384, (it + 1) * 64);
        const short* As = Sc;
        const short* Bs = Sc + 8192;
#pragma unroll
        for (int ks = 0; ks < 2; ++ks) {
            bf8 af[4], bfr[4];
#pragma unroll
            for (int mt = 0; mt < 4; ++mt)
                af[mt] = *(const bf8*)(As + (wm * 64 + mt * 16 + l16) * 64 +
                                       (((ks * 4 + quad) ^ rx) * 8));
#pragma unroll
            for (int nt = 0; nt < 4; ++nt)
                bfr[nt] = *(const bf8*)(Bs + (wn * 64 + nt * 16 + l16) * 64 +
                                        (((ks * 4 + quad) ^ rx) * 8));
#pragma unroll
            for (int mt = 0; mt < 4; ++mt)
#pragma unroll
                for (int nt = 0; nt < 4; ++nt)
                    acc[mt][nt] = __builtin_amdgcn_mfma_f32_16x16x32_bf16(
                        af[mt], bfr[nt], acc[mt][nt], 0, 0, 0);
        }
    }
    __syncthreads();   // callers may reuse smem right after return
}

// ---- QKV projection: [8192,768] @ [768,2304], tile 256x288, BK=64,
//      grid EXACTLY 256 blocks (32 m x 8 n) -> no dispatch tail.
// 8 waves as 4M x 2N; per-wave 64x144 output = acc[4][9].
// Phases per K-tile: (m0,n0-4)(m1,n0-4)(m0,n5-8)(m1,n5-8); 20/20/16/16 MFMA.
//   stage slots: ph1 (t+1).B1  ph2 (t+1).A0  ph3 (t+1).A1  ph4 (t+2).B0.
// B staging: waves 0-1 do 3 calls, 2-7 do 2 -> per-wave counted vmcnt.
// LDS 136 KiB: buf b at b*34816 shorts = [A 256x64 | B 288x64], slot^row XOR
// swizzle (pre-swizzled global src, linear LDS dest).
__global__ __launch_bounds__(512, 2) void k_gemm_qkv(
        const short* __restrict__ xb, const short* __restrict__ wtq,
        short* __restrict__ qb, short* __restrict__ kb, short* __restrict__ vt) {
    __shared__ short lds[69632];   // 136 KiB
    const int tid = threadIdx.x, lane = tid & 63;
    const int l16 = lane & 15, quad = lane >> 4, rx = l16 & 7;
    const int wv = tid >> 6, wm = wv >> 1, wn = wv & 1;   // 4M x 2N waves

    // XCD-aware bijective swizzle: 256 blocks = 8 XCDs x 32.
    const int wg = blockIdx.x;
    const int swz = (wg & 7) * 32 + (wg >> 3);
    const int mI = swz >> 3, nI = swz & 7;
    const int m0 = mI * 256, n0 = nI * 288;

    const short* gA = xb + m0 * 768;
    const short* gB = wtq + n0 * 768;

    // stage one 128x64 A half-tile: 1024 chunks, 2/thread.
    auto stageA = [&](int buf, int half, int k0) {
        short* dst = lds + buf * 34816 + half * 8192;
        const short* src = gA + half * 98304 + k0;
#pragma unroll
        for (int j = 0; j < 2; ++j) {
            int p = j * 512 + tid;
            int row = p >> 3;
            int gc = (p & 7) ^ (row & 7);
            async16(src + row * 768 + gc * 8, dst + p * 8);
        }
    };
    // stage one 144x64 B half-tile: 1152 chunks; waves 0-1 take the extra 128.
    auto stageB = [&](int buf, int half, int k0) {
        short* dst = lds + buf * 34816 + 16384 + half * 9216;
        const short* src = gB + half * 110592 + k0;
#pragma unroll
        for (int j = 0; j < 2; ++j) {
            int p = j * 512 + tid;
            int row = p >> 3;
            int gc = (p & 7) ^ (row & 7);
            async16(src + row * 768 + gc * 8, dst + p * 8);
        }
        if (tid < 128) {              // waves 0,1: wave-uniform, lane-contig
            int p = 1024 + tid;
            int row = p >> 3;
            int gc = (p & 7) ^ (row & 7);
            async16(src + row * 768 + gc * 8, dst + p * 8);
        }
    };

    f4 z = {0.f, 0.f, 0.f, 0.f};
    f4 acc[4][9];
#pragma unroll
    for (int mf = 0; mf < 4; ++mf)
#pragma unroll
        for (int nf = 0; nf < 9; ++nf) acc[mf][nf] = z;

    // prologue: t0 fully + t1.B0; leave t1.B0 in flight
    stageA(0, 0, 0); stageA(0, 1, 0);
    stageB(0, 0, 0); stageB(0, 1, 0);
    stageB(1, 0, 64);
    if (wv < 2) asm volatile("s_waitcnt vmcnt(3)" ::: "memory");
    else        asm volatile("s_waitcnt vmcnt(2)" ::: "memory");
    __builtin_amdgcn_s_barrier();

#pragma unroll 2
    for (int t = 0; t < 12; ++t) {
        const short* Ab = lds + (t & 1) * 34816;
        const short* Bb = Ab + 16384;
        auto rdA = [&](int mf, int ks) {
            return *(const bf8*)(Ab + (wm * 64 + mf * 16 + l16) * 64 +
                                 (((ks * 4 + quad) ^ rx) << 3));
        };
        auto rdB = [&](int nf, int ks) {
            return *(const bf8*)(Bb + (wn * 144 + nf * 16 + l16) * 64 +
                                 (((ks * 4 + quad) ^ rx) << 3));
        };
        bf8 af[4][2], bfr[9][2];

        // ---------- phase 1: (mf 0-1) x (nf 0-4) ----------
#pragma unroll
        for (int mf = 0; mf < 2; ++mf) { af[mf][0] = rdA(mf, 0); af[mf][1] = rdA(mf, 1); }
#pragma unroll
        for (int nf = 0; nf < 5; ++nf) { bfr[nf][0] = rdB(nf, 0); bfr[nf][1] = rdB(nf, 1); }
        if (t < 11) stageB((t + 1) & 1, 1, (t + 1) * 64);
        __builtin_amdgcn_s_barrier();
        __builtin_amdgcn_s_setprio(1);
#pragma unroll
        for (int mf = 0; mf < 2; ++mf)
#pragma unroll
            for (int nf = 0; nf < 5; ++nf) {
                acc[mf][nf] = __builtin_amdgcn_mfma_f32_16x16x32_bf16(
                    af[mf][0], bfr[nf][0], acc[mf][nf], 0, 0, 0);
                acc[mf][nf] = __builtin_amdgcn_mfma_f32_16x16x32_bf16(
                    af[mf][1], bfr[nf][1], acc[mf][nf], 0, 0, 0);
            }
        __builtin_amdgcn_s_setprio(0);
        __builtin_amdgcn_s_barrier();

        // ---------- phase 2: (mf 2-3) x (nf 0-4) ----------
#pragma unroll
        for (int mf = 2; mf < 4; ++mf) { af[mf][0] = rdA(mf, 0); af[mf][1] = rdA(mf, 1); }
        if (t < 11) stageA((t + 1) & 1, 0, (t + 1) * 64);
        __builtin_amdgcn_s_barrier();
        __builtin_amdgcn_s_setprio(1);
#pragma unroll
        for (int mf = 2; mf < 4; ++mf)
#pragma unroll
            for (int nf = 0; nf < 5; ++nf) {
                acc[mf][nf] = __builtin_amdgcn_mfma_f32_16x16x32_bf16(
                    af[mf][0], bfr[nf][0], acc[mf][nf], 0, 0, 0);
                acc[mf][nf] = __builtin_amdgcn_mfma_f32_16x16x32_bf16(
                    af[mf][1], bfr[nf][1], acc[mf][nf], 0, 0, 0);
            }
        __builtin_amdgcn_s_setprio(0);
        __builtin_amdgcn_s_barrier();

        // ---------- phase 3: (mf 0-1) x (nf 5-8) ----------
#pragma unroll
        for (int nf = 5; nf < 9; ++nf) { bfr[nf][0] = rdB(nf, 0); bfr[nf][1] = rdB(nf, 1); }
        if (t < 11) stageA((t + 1) & 1, 1, (t + 1) * 64);
        __builtin_amdgcn_s_barrier();
        __builtin_amdgcn_s_setprio(1);
#pragma unroll
        for (int mf = 0; mf < 2; ++mf)
#pragma unroll
            for (int nf = 5; nf < 9; ++nf) {
                acc[mf][nf] = __builtin_amdgcn_mfma_f32_16x16x32_bf16(
                    af[mf][0], bfr[nf][0], acc[mf][nf], 0, 0, 0);
                acc[mf][nf] = __builtin_amdgcn_mfma_f32_16x16x32_bf16(
                    af[mf][1], bfr[nf][1], acc[mf][nf], 0, 0, 0);
            }
        __builtin_amdgcn_s_setprio(0);
        __builtin_amdgcn_s_barrier();

        // ---------- phase 4: (mf 2-3) x (nf 5-8); counted vmcnt ----------
        if (t < 10) stageB(t & 1, 0, (t + 2) * 64);
        __builtin_amdgcn_s_barrier();
        __builtin_amdgcn_s_setprio(1);
#pragma unroll
        for (int mf = 2; mf < 4; ++mf)
#pragma unroll
            for (int nf = 5; nf < 9; ++nf) {
                acc[mf][nf] = __builtin_amdgcn_mfma_f32_16x16x32_bf16(
                    af[mf][0], bfr[nf][0], acc[mf][nf], 0, 0, 0);
                acc[mf][nf] = __builtin_amdgcn_mfma_f32_16x16x32_bf16(
                    af[mf][1], bfr[nf][1], acc[mf][nf], 0, 0, 0);
            }
        __builtin_amdgcn_s_setprio(0);
        // retire everything except ph4's (t+2).B0 -> tile t+1 fully resident
        if (t < 10) {
            if (wv < 2) asm volatile("s_waitcnt vmcnt(3)" ::: "memory");
            else        asm volatile("s_waitcnt vmcnt(2)" ::: "memory");
        } else if (t == 10) {
            asm volatile("s_waitcnt vmcnt(0)" ::: "memory");
        }
        __builtin_amdgcn_s_barrier();
    }

    // ---------------- epilogue ----------------
    const int bI = m0 >> 10, nn0 = m0 & 1023;
    // q/k frags (per-frag type; 768 % 16 == 0 so frags never straddle)
#pragma unroll
    for (int nf = 0; nf < 9; ++nf) {
        const int ct = n0 + wn * 144 + nf * 16;
        if (ct < 1536) {
            const int which = (ct >= 768) ? 1 : 0;
            const int h = (ct - which * 768) >> 6;
            const int hd = (ct & 63) + l16;
            short* dst = (which ? kb : qb) + ((bI * 12 + h) * 1024) * 64 + hd;
#pragma unroll
            for (int mf = 0; mf < 4; ++mf)
#pragma unroll
                for (int r = 0; r < 4; ++r) {
                    const int nn = nn0 + wm * 64 + mf * 16 + quad * 4 + r;
                    const float val = acc[mf][nf][r];
                    dst[nn * 64] = bf16_of(which ? val : val * QSCALE);
                }
        }
    }
    // v frags: transpose through LDS in 96-col passes (96x264 shorts = 50 KB)
    const int vstart = (n0 >= 1536) ? n0 : 1536;
    const int npass = (n0 + 288 > vstart) ? (n0 + 288 - vstart) / 96 : 0;
    for (int p = 0; p < npass; ++p) {
        __syncthreads();
        const int c0 = vstart + p * 96;
#pragma unroll
        for (int nf = 0; nf < 9; ++nf) {
            const int ct = n0 + wn * 144 + nf * 16;
            if (ct >= c0 && ct < c0 + 96) {
                const int lc = ct - c0 + l16;
#pragma unroll
                for (int mf = 0; mf < 4; ++mf)
#pragma unroll
                    for (int r = 0; r < 4; ++r) {
                        const int rl = wm * 64 + mf * 16 + quad * 4 + r;
                        lds[lc * 264 + rl] = bf16_of(acc[mf][nf][r]);
                    }
            }
        }
        __syncthreads();
        const int vg0 = c0 - 1536;
#pragma unroll
        for (int u = 0; u < 6; ++u) {
            const int idx = u * 512 + tid;       // 96 cols x 32 chunks
            const int lc = idx >> 5, ck = idx & 31;
            const int vg = vg0 + lc;
            const int h = vg >> 6, hd = vg & 63;
            bf8 vv = *(const bf8*)(lds + lc * 264 + ck * 8);
            *(bf8*)(vt + ((bI * 12 + h) * 64 + hd) * 1024 + nn0 + ck * 8) = vv;
        }
    }
}

// ---- final projection: [8192,768] @ [768,768] + bias -> fp32 out ----
__global__ __launch_bounds__(256) void k_gemm_final(
        const short* __restrict__ attn, const short* __restrict__ wtm,
        const float* __restrict__ bias, float* __restrict__ out) {
    __shared__ short smem[32768];
    const int lane = threadIdx.x & 63;
    const int l16 = lane & 15, quad = lane >> 4;
    const int wm = (threadIdx.x >> 6) & 1, wn = threadIdx.x >> 7;
    const int m0 = blockIdx.y * 128, n0 = blockIdx.x * 128;
    f4 z = {0.f, 0.f, 0.f, 0.f};
    f4 acc[4][4] = {{z,z,z,z},{z,z,z,z},{z,z,z,z},{z,z,z,z}};
    gemm128(attn + m0 * 768, wtm + n0 * 768, smem, acc);
#pragma unroll
    for (int mt = 0; mt < 4; ++mt) {
#pragma unroll
        for (int r = 0; r < 4; ++r) {
            const int row = m0 + wm * 64 + mt * 16 + quad * 4 + r;
#pragma unroll
            for (int nt = 0; nt < 4; ++nt) {
                const int e = n0 + wn * 64 + nt * 16 + l16;
                out[row * 768 + e] = acc[mt][nt][r] + bias[e];
            }
        }
    }
}

// ---- flash attention: 4 waves x 32 q-rows (256-thread block), grid (96,8)
//      = 768 blocks -> exactly 3 co-resident blocks/CU (launch_bounds(256,3)).
// Two q-groups per wave SHARE the K and V LDS fragments: ds_read per MFMA
// halves, per-wave ILP doubles (two independent QK->exp->PV chains), barrier
// cost per unit work halves. Numerics bit-identical to the 16-row version
// (same sigma/swizzle mappings, same ones-MFMA rowsum per group).
// S-MFMA set A uses K rows sigma(p)=8*(p>>2)+(p&3), set B rows sigma(p)+4.
// lane(l16,quad) regs [A0..A3,B0..B3] = P[m=l16][j=quad*8+0..7]: the PV
// B-operand directly -- no cross-lane transform needed.
// LDS swizzle f(row)=4*((row>>3)&1)+(row&3) keeps sigma-reads at 2 lanes/bank.
__global__ __launch_bounds__(256, 3) void k_attn(const short* __restrict__ qb,
                                                 const short* __restrict__ kb,
                                                 const short* __restrict__ vt,
                                                 short* __restrict__ attn) {
    __shared__ short Ks[2][4096];     // [64 keys][8 slots], f-swizzled
    __shared__ short Vs[2][4096];     // [64 dims][8 slots], f-swizzled
    const int tid = threadIdx.x, wave = tid >> 6, lane = tid & 63;
    const int l16 = lane & 15, quad = lane >> 4;
    const int bh = blockIdx.x;             // b*12 + h
    const int b = bh / 12, h = bh - b * 12;
    const int m_base = blockIdx.y * 128 + wave * 32;  // 32 q-rows per wave
    const short* qh = qb + bh * 65536;
    const short* kh = kb + bh * 65536;
    const short* vh = vt + bh * 65536;     // [64][1024]

    // K-read offsets: set A row rA = sigma(l16), set B row rA+4 (f identical)
    const int rA = ((l16 >> 2) << 3) + (l16 & 3);
    const int fK = (((rA >> 3) & 1) << 2) + (rA & 3);
    const int sK = (quad ^ fK) * 8;              // slot*8 for d-chunk=quad
    const int oAlo = rA * 64 + sK;               // d 0..31
    const int oAhi = rA * 64 + (sK ^ 32);        // d 32..63 (slot^4)
    const int oBlo = oAlo + 256, oBhi = oAhi + 256;  // row+4
    // V-read offset: row = dt*16+l16, chunk = (jj>>3)+quad
    const int fV = (((l16 >> 3) & 1) << 2) + (l16 & 3);
    const int oV = l16 * 64 + ((quad ^ fV) * 8); // jj=32 -> ^32

    // Q^T b-frags for both 16-row groups (fixed for whole loop)
    const short* qp0 = qh + (m_base + l16) * 64 + quad * 8;
    bf8 qf00 = *(const bf8*)(qp0);
    bf8 qf01 = *(const bf8*)(qp0 + 32);
    const short* qp1 = qp0 + 16 * 64;
    bf8 qf10 = *(const bf8*)(qp1);
    bf8 qf11 = *(const bf8*)(qp1 + 32);

    union { bf8 v; short h[8]; } onef;
#pragma unroll
    for (int i = 0; i < 8; ++i) onef.h[i] = (short)0x3F80;  // bf16 1.0

    f4 z = {0.f, 0.f, 0.f, 0.f};
    f4 acc0[4] = {z, z, z, z};             // out^T group 0: 4 d-tiles
    f4 acc1[4] = {z, z, z, z};             // out^T group 1
    f4 accl0 = z, accl1 = z;               // P row-sums via ones-MFMA

    auto stage = [&](int buf, int j0) {
        // 256 threads x 2: 512 chunks each for K and V
#pragma unroll
        for (int j = 0; j < 2; ++j) {
            int idx = j * 256 + tid;
            int row = idx >> 3;
            int fr = (((row >> 3) & 1) << 2) + (row & 3);
            int gc = (idx & 7) ^ fr;        // slot idx&7 holds chunk gc
            async16(kh + (j0 + row) * 64 + gc * 8, Ks[buf] + idx * 8);
            async16(vh + row * 1024 + j0 + gc * 8, Vs[buf] + idx * 8);
        }
    };

    stage(0, 0);
    int cur = 0;
    for (int it = 0; it < 16; ++it) {
        __builtin_amdgcn_s_waitcnt(0);         // own DMA for tile[cur] drained
        __syncthreads();                       // => tile[cur] resident for all
        if (it + 1 < 16) stage(cur ^ 1, (it + 1) * 64);  // overlaps compute
        const short* Kc = Ks[cur];
        const short* Vc = Vs[cur];

#pragma unroll
        for (int jj = 0; jj < 64; jj += 32) {
            const short* kjj = Kc + jj * 64;
            bf8 kAlo = *(const bf8*)(kjj + oAlo);
            bf8 kAhi = *(const bf8*)(kjj + oAhi);
            bf8 kBlo = *(const bf8*)(kjj + oBlo);
            bf8 kBhi = *(const bf8*)(kjj + oBhi);
            bf8 vf0 = *(const bf8*)(Vc + 0 * 1024 + (oV ^ (jj ? 32 : 0)));
            bf8 vf1 = *(const bf8*)(Vc + 1 * 1024 + (oV ^ (jj ? 32 : 0)));
            bf8 vf2 = *(const bf8*)(Vc + 2 * 1024 + (oV ^ (jj ? 32 : 0)));
            bf8 vf3 = *(const bf8*)(Vc + 3 * 1024 + (oV ^ (jj ? 32 : 0)));

            // ----- group 0 -----
            {
                f4 sA = z, sB = z;
                sA = __builtin_amdgcn_mfma_f32_16x16x32_bf16(kAlo, qf00, sA, 0, 0, 0);
                sA = __builtin_amdgcn_mfma_f32_16x16x32_bf16(kAhi, qf01, sA, 0, 0, 0);
                sB = __builtin_amdgcn_mfma_f32_16x16x32_bf16(kBlo, qf00, sB, 0, 0, 0);
                sB = __builtin_amdgcn_mfma_f32_16x16x32_bf16(kBhi, qf01, sB, 0, 0, 0);
                float a0 = __builtin_amdgcn_exp2f(sA[0]);
                float a1 = __builtin_amdgcn_exp2f(sA[1]);
                float a2 = __builtin_amdgcn_exp2f(sA[2]);
                float a3 = __builtin_amdgcn_exp2f(sA[3]);
                float b0 = __builtin_amdgcn_exp2f(sB[0]);
                float b1 = __builtin_amdgcn_exp2f(sB[1]);
                float b2 = __builtin_amdgcn_exp2f(sB[2]);
                float b3 = __builtin_amdgcn_exp2f(sB[3]);
                union { bf8 v; unsigned u[4]; } p;
                p.u[0] = bfpk(a0, a1); p.u[1] = bfpk(a2, a3);
                p.u[2] = bfpk(b0, b1); p.u[3] = bfpk(b2, b3);
                accl0 = __builtin_amdgcn_mfma_f32_16x16x32_bf16(
                    onef.v, p.v, accl0, 0, 0, 0);
                acc0[0] = __builtin_amdgcn_mfma_f32_16x16x32_bf16(vf0, p.v, acc0[0], 0, 0, 0);
                acc0[1] = __builtin_amdgcn_mfma_f32_16x16x32_bf16(vf1, p.v, acc0[1], 0, 0, 0);
                acc0[2] = __builtin_amdgcn_mfma_f32_16x16x32_bf16(vf2, p.v, acc0[2], 0, 0, 0);
                acc0[3] = __builtin_amdgcn_mfma_f32_16x16x32_bf16(vf3, p.v, acc0[3], 0, 0, 0);
            }
            // ----- group 1 (shares kA/kB/vf frags) -----
            {
                f4 sA = z, sB = z;
                sA = __builtin_amdgcn_mfma_f32_16x16x32_bf16(kAlo, qf10, sA, 0, 0, 0);
                sA = __builtin_amdgcn_mfma_f32_16x16x32_bf16(kAhi, qf11, sA, 0, 0, 0);
                sB = __builtin_amdgcn_mfma_f32_16x16x32_bf16(kBlo, qf10, sB, 0, 0, 0);
                sB = __builtin_amdgcn_mfma_f32_16x16x32_bf16(kBhi, qf11, sB, 0, 0, 0);
                float a0 = __builtin_amdgcn_exp2f(sA[0]);
                float a1 = __builtin_amdgcn_exp2f(sA[1]);
                float a2 = __builtin_amdgcn_exp2f(sA[2]);
                float a3 = __builtin_amdgcn_exp2f(sA[3]);
                float b0 = __builtin_amdgcn_exp2f(sB[0]);
                float b1 = __builtin_amdgcn_exp2f(sB[1]);
                float b2 = __builtin_amdgcn_exp2f(sB[2]);
                float b3 = __builtin_amdgcn_exp2f(sB[3]);
                union { bf8 v; unsigned u[4]; } p;
                p.u[0] = bfpk(a0, a1); p.u[1] = bfpk(a2, a3);
                p.u[2] = bfpk(b0, b1); p.u[3] = bfpk(b2, b3);
                accl1 = __builtin_amdgcn_mfma_f32_16x16x32_bf16(
                    onef.v, p.v, accl1, 0, 0, 0);
                acc1[0] = __builtin_amdgcn_mfma_f32_16x16x32_bf16(vf0, p.v, acc1[0], 0, 0, 0);
                acc1[1] = __builtin_amdgcn_mfma_f32_16x16x32_bf16(vf1, p.v, acc1[1], 0, 0, 0);
                acc1[2] = __builtin_amdgcn_mfma_f32_16x16x32_bf16(vf2, p.v, acc1[2], 0, 0, 0);
                acc1[3] = __builtin_amdgcn_mfma_f32_16x16x32_bf16(vf3, p.v, acc1[3], 0, 0, 0);
            }
        }
        cur ^= 1;
    }

    const float inv0 = 1.f / accl0[0];
    const float inv1 = 1.f / accl1[0];
    const int row0 = (b << 10) + m_base + l16;
    short* op0 = attn + row0 * 768 + h * 64 + quad * 4;
    short* op1 = op0 + 16 * 768;
#pragma unroll
    for (int dt = 0; dt < 4; ++dt)
#pragma unroll
        for (int r = 0; r < 4; ++r) {
            op0[dt * 16 + r] = bf16_of(acc0[dt][r] * inv0);
            op1[dt * 16 + r] = bf16_of(acc1[dt][r] * inv1);
        }
}

extern "C" void kernel_launch(void* const* d_in, const int* in_sizes, int n_in,
                              void* d_out, int out_size, void* d_ws, size_t ws_size,
                              hipStream_t stream) {
    const float* x    = (const float*)d_in[0];   // [8,1024,768]
    const float* gate = (const float*)d_in[1];   // [8,1024]
    const float* Wqkv = (const float*)d_in[2];   // [768,2304]
    const float* Wmsa = (const float*)d_in[3];   // [768,768]
    const float* bmsa = (const float*)d_in[4];   // [768]
    float* out = (float*)d_out;

    char* ws = (char*)d_ws;
    short* xb  = (short*)(ws);
    short* wtq = (short*)(ws + 12582912);
    short* wtm = (short*)(ws + 16121856);
    short* qb  = (short*)(ws + 17301504);
    short* kb  = (short*)(ws + 29884416);
    short* vt  = (short*)(ws + 42467328);
    short* attn = xb;  // xb fully consumed by k_gemm_qkv before k_attn writes

    k_prep<<<3648, 256, 0, stream>>>(x, gate, xb, Wqkv, wtq, Wmsa, wtm);
    k_gemm_qkv<<<256, 512, 0, stream>>>(xb, wtq, qb, kb, vt);
    k_attn<<<dim3(96, 8), 256, 0, stream>>>(qb, kb, vt, attn);
    k_gemm_final<<<dim3(6, 64), 256, 0, stream>>>(attn, wtm, bmsa, out);
}